// Round 6
// baseline (628.424 us; speedup 1.0000x reference)
//
#include <hip/hip_runtime.h>

// Problem constants
#define BATCH 4096
#define NI 1024
#define HID 2048
#define TSTEPS 20
#define NA 45
#define SR 136     // fused S row stride in bf16 elems (128 + 8 pad; 272B = 16B-aligned, bank stride 4)
#define SWROWS 21  // 20 t-rows + 1 zero row for masked A-frag reads

typedef __bf16 bf16x8 __attribute__((ext_vector_type(8)));
typedef float floatx4 __attribute__((ext_vector_type(4)));

__device__ __forceinline__ unsigned short f2bf(float x) {
    union { float f; unsigned int u; } un; un.f = x;
    unsigned int r = un.u + 0x7FFFu + ((un.u >> 16) & 1u);
    return (unsigned short)(r >> 16);
}

__device__ __forceinline__ ushort4 cvt4(float4 v) {
    ushort4 o;
    o.x = f2bf(v.x); o.y = f2bf(v.y); o.z = f2bf(v.z); o.w = f2bf(v.w);
    return o;
}

// ---------------------------------------------------------------------------
// Kernel 1 (merged prep): transpose_w1 (blocks [0,2048)), convert_w2
// (blocks [2048,2056)), scan (blocks [2056,2072)).
// scan: exact fp32 replication of the 20-step state machine. Emits per-b:
//   U4[b][20] float4 = (ac0, ac1, delta-0.0625, chosen)  [absolute state]
//   BI[b][12] ints: 0 selLo, 1 selHi (3b/t swap-slot or 7), 2 cAB, 3 cCD,
//   4 cE (packed (old<<8)|new cols), 5 nAlive (alive is monotone!), 6 ns,
//   7..10 dacPk (6b/dac, 5 per int), 11 pad.
// x-col offsets of extras: ac0=0 ac1=1 fb=2..4 lr=5..7 jp=8..9 ss=10..13
// at=14..45 delta=46 chosen=47.
// ---------------------------------------------------------------------------
__global__ void prep_kernel(const float* __restrict__ W1, unsigned short* __restrict__ Wt,
                            const float* __restrict__ W2, unsigned short* __restrict__ W2T,
                            const float* __restrict__ camera,
                            const int* __restrict__ fb_in, const int* __restrict__ lr_in,
                            const int* __restrict__ jp_in, const int* __restrict__ ss_in,
                            const int* __restrict__ at_in,
                            float* __restrict__ U4f, int* __restrict__ BI) {
    __shared__ float tile[32][33];
    int bid = blockIdx.x, tid = threadIdx.x;
    if (bid < 2048) {
        int k0 = (bid & 31) * 32, n0 = (bid >> 5) * 32;
        int tx = tid & 31, ty = tid >> 5;  // (32, 8)
        for (int i = 0; i < 4; i++)
            tile[ty + 8 * i][tx] = W1[(size_t)(k0 + ty + 8 * i) * HID + n0 + tx];
        __syncthreads();
        for (int i = 0; i < 4; i++) {
            int n = ty + 8 * i;
            Wt[(size_t)(n0 + n) * NI + k0 + tx] = f2bf(tile[tx][n]);
        }
    } else if (bid < 2056) {
        int k = (bid - 2048) * 256 + tid;  // 0..2047
        for (int n = 0; n < 48; n++)
            W2T[(size_t)n * HID + k] = (n < NA) ? f2bf(W2[(size_t)k * NA + n]) : (unsigned short)0;
    } else {
        int b = (bid - 2056) * 256 + tid;
        if (b >= BATCH) return;
        float cam0 = camera[2 * b], cam1 = camera[2 * b + 1];
        int afb = fb_in[b], alr = lr_in[b], ajp = jp_in[b], ass = ss_in[b], aat = at_in[b];
        float ac0 = 0.f, ac1 = 0.f, delta = 0.0625f;  // MIN_DELTA = 0.5/8
        int rfb = 0, rlr = 0, rjp = 0, rss = 0, rat = 0;
        bool chosen = false, commited = false;
        int cam_steps = 0;
        int chgPending = -1;
        bool camzero = (fabsf(cam0) < 1e-5f) && (fabsf(cam1) < 1e-5f);
        int ns = 0, selLo = 0, selHi = 0, nAlive = 0;
        int swapC[5] = {0, 0, 0, 0, 0};
        int dacPk[4] = {0, 0, 0, 0};
#pragma unroll
        for (int t = 0; t < TSTEPS; t++) {
            // entering step t: apply pending swap to schedule
            int sel = 7;
            if (chgPending >= 0) { swapC[ns] = chgPending; sel = ns; ns++; chgPending = -1; }
            if (t < 10) selLo |= sel << (3 * t); else selHi |= sel << (3 * (t - 10));
            ((float4*)U4f)[b * TSTEPS + t] =
                make_float4(ac0, ac1, delta - 0.0625f, chosen ? 1.f : 0.f);
            nAlive += commited ? 0 : 1;
            bool commit = (camzero || cam_steps >= 6) &&
                          rfb == afb && rlr == alr && rjp == ajp && rss == ass && rat == aat;
            int dac = 0; bool modified = commit;
            if (!modified && rfb != afb) { dac = (afb == 0 ? rfb - 1 + 6  : afb - 1 + 6 ); chgPending = ((2  + rfb) << 8) | (2  + afb); rfb = afb; modified = true; }
            if (!modified && rlr != alr) { dac = (alr == 0 ? rlr - 1 + 8  : alr - 1 + 8 ); chgPending = ((5  + rlr) << 8) | (5  + alr); rlr = alr; modified = true; }
            if (!modified && rjp != ajp) { dac = (ajp == 0 ? rjp - 1 + 10 : ajp - 1 + 10); chgPending = ((8  + rjp) << 8) | (8  + ajp); rjp = ajp; modified = true; }
            if (!modified && rss != ass) { dac = (ass == 0 ? rss - 1 + 11 : ass - 1 + 11); chgPending = ((10 + rss) << 8) | (10 + ass); rss = ass; modified = true; }
            if (!modified && rat != aat) { dac = (aat == 0 ? rat - 1 + 14 : aat - 1 + 14); chgPending = ((14 + rat) << 8) | (14 + aat); rat = aat; modified = true; }
            // NOTE: reference compares BOTH cam0 and cam1 against ac0 (as-is)
            if (!modified && !chosen &&
                (fabsf(cam0 - ac0) > delta * 2.f || fabsf(cam1 - ac0) > delta * 2.f)) {
                dac = 5; delta = fminf(delta * 2.f, 0.5f); modified = true;
            }
            if (!modified) {
                bool incX = cam0 >= ac0, incY = cam1 >= ac1;
                dac = 1 + (incX ? 1 : 0) + (incY ? 2 : 0);
                ac0 += incX ? delta : -delta;
                ac1 += incY ? delta : -delta;
                delta *= 0.5f;
                chosen = true;
                cam_steps++;
            }
            commited = commited || commit;
            dacPk[t / 5] |= dac << (6 * (t % 5));
        }
        int* o = BI + b * 12;
        o[0] = selLo; o[1] = selHi;
        o[2] = swapC[0] | (swapC[1] << 16);
        o[3] = swapC[2] | (swapC[3] << 16);
        o[4] = swapC[4];
        o[5] = nAlive; o[6] = ns;
        o[7] = dacPk[0]; o[8] = dacPk[1]; o[9] = dacPk[2]; o[10] = dacPk[3];
        o[11] = 0;
    }
}

// ---------------------------------------------------------------------------
// Kernel 2: base[4096][2048] = fc_input(fp32, converted in-register) @
// W1[:1024] (bf16 MFMA). Epilogue folds t=0 constants: + b1 + initial
// one-hot rows (2,5,8,10,14) + 0.0625*w_delta. (Unchanged from R5 — passing.)
// ---------------------------------------------------------------------------
__global__ __launch_bounds__(256) void gemm_base(const float* __restrict__ A,
                                                 const unsigned short* __restrict__ Wt,
                                                 const float* __restrict__ W1,
                                                 const float* __restrict__ b1,
                                                 float* __restrict__ C) {
    __shared__ __align__(16) __bf16 At[128 * 32];
    __shared__ __align__(16) __bf16 Bt[128 * 32];
    int bn = blockIdx.x, bm = blockIdx.y;
    int m0 = bm * 128, n0 = bn * 128;
    int tid = threadIdx.x;
    int wave = tid >> 6, lane = tid & 63;
    int wr = wave >> 1, wc = wave & 1;
    int l15 = lane & 15, q = lane >> 4;
    floatx4 acc[4][4];
    for (int a = 0; a < 4; a++) for (int c = 0; c < 4; c++) acc[a][c] = (floatx4){0.f, 0.f, 0.f, 0.f};
    int arow = tid >> 1, aseg = (tid & 1) * 16;
    for (int k0 = 0; k0 < NI; k0 += 32) {
        __syncthreads();
#pragma unroll
        for (int i = 0; i < 2; i++) {
            int c = i * 256 + tid;
            int row = c >> 2, quarter = c & 3;
            const unsigned short* gB = &Wt[(size_t)(n0 + row) * NI + k0 + quarter * 8];
            __builtin_amdgcn_global_load_lds(
                (const __attribute__((address_space(1))) unsigned int*)gB,
                (__attribute__((address_space(3))) unsigned int*)&Bt[c * 8], 16, 0, 0);
        }
        const float* ga = &A[(size_t)(m0 + arow) * NI + k0 + aseg];
        float4 f0 = *(const float4*)&ga[0];
        float4 f1 = *(const float4*)&ga[4];
        float4 f2 = *(const float4*)&ga[8];
        float4 f3 = *(const float4*)&ga[12];
        union { ushort4 s4[4]; uint4 v[2]; } pk;
        pk.s4[0] = cvt4(f0); pk.s4[1] = cvt4(f1); pk.s4[2] = cvt4(f2); pk.s4[3] = cvt4(f3);
        *(uint4*)&At[arow * 32 + aseg]     = pk.v[0];
        *(uint4*)&At[arow * 32 + aseg + 8] = pk.v[1];
        __syncthreads();
        bf16x8 af[4], bf[4];
        for (int mr = 0; mr < 4; mr++)
            af[mr] = *(const bf16x8*)&At[(wr * 64 + mr * 16 + l15) * 32 + q * 8];
        for (int nc = 0; nc < 4; nc++)
            bf[nc] = *(const bf16x8*)&Bt[(wc * 64 + nc * 16 + l15) * 32 + q * 8];
        for (int mr = 0; mr < 4; mr++)
            for (int nc = 0; nc < 4; nc++)
                acc[mr][nc] = __builtin_amdgcn_mfma_f32_16x16x32_bf16(af[mr], bf[nc], acc[mr][nc], 0, 0, 0);
    }
    for (int nc = 0; nc < 4; nc++) {
        int col = n0 + wc * 64 + nc * 16 + l15;
        const float* We = W1 + (size_t)NI * HID + col;
        float cv = b1[col] + We[2 * HID] + We[5 * HID] + We[8 * HID] + We[10 * HID]
                 + We[14 * HID] + 0.0625f * We[46 * HID];
        for (int mr = 0; mr < 4; mr++)
            for (int r = 0; r < 4; r++) {
                int row = m0 + wr * 64 + mr * 16 + q * 4 + r;
                C[(size_t)row * HID + col] = acc[mr][nc][r] + cv;
            }
    }
}

// ---------------------------------------------------------------------------
// Kernel 3: BARRIER-FREE fused MLP + CE. One WAVE per b (4 waves/block),
// zero __syncthreads — all LDS use is wave-private (DS ops are in-order
// within a wave). Per wave: 16 iterations over j-chunks of 128:
//   phase A: h[t] = (base + running swap-sum) + u[t]·w  (2 j/lane, packed
//   b32 S writes); phase B: 24 MFMA vs W2T (full K stays in this wave).
// Epilogue: logits live in acc regs (col=class=nt*16+l15, row=t=mt*16+q*4+r);
// CE via in-register 16-lane shuffle reductions. alive is monotone -> count.
// ---------------------------------------------------------------------------
__global__ __launch_bounds__(256, 5) void fused_mlp(const float* __restrict__ base,
                                                    const float* __restrict__ W1,
                                                    const unsigned short* __restrict__ W2T,
                                                    const float* __restrict__ b2,
                                                    const float* __restrict__ U4f,
                                                    const int* __restrict__ BI,
                                                    float* __restrict__ loss_out) {
    __shared__ __align__(16) __bf16 S[4 * SWROWS * SR];  // 22,848 B (wave-private slabs)
    __shared__ __align__(16) float4 u4s[4][TSTEPS];      //  1,280 B
    __shared__ int dacW[4][TSTEPS];                      //    320 B

    int tid = threadIdx.x;
    int wv = tid >> 6, lane = tid & 63, l15 = lane & 15, q = lane >> 4;
    int b = blockIdx.x * 4 + wv;
    __bf16* Sw = S + wv * (SWROWS * SR);

    // --- per-b uniform scalars ---
    const int* bi = BI + b * 12;
    int selLo  = __builtin_amdgcn_readfirstlane(bi[0]);
    int selHi  = __builtin_amdgcn_readfirstlane(bi[1]);
    int cAB    = __builtin_amdgcn_readfirstlane(bi[2]);
    int cCD    = __builtin_amdgcn_readfirstlane(bi[3]);
    int cE     = __builtin_amdgcn_readfirstlane(bi[4]);
    int nAlive = __builtin_amdgcn_readfirstlane(bi[5]);
    int ns     = __builtin_amdgcn_readfirstlane(bi[6]);
    int rAn = cAB & 255,         rAo = (cAB >> 8) & 255;
    int rBn = (cAB >> 16) & 255, rBo = (cAB >> 24) & 255;
    int rCn = cCD & 255,         rCo = (cCD >> 8) & 255;
    int rDn = (cCD >> 16) & 255, rDo = (cCD >> 24) & 255;
    int rEn = cE & 255,          rEo = (cE >> 8) & 255;

    // --- wave-private LDS setup (no barrier: same-wave DS ordering) ---
    if (lane < TSTEPS) {
        u4s[wv][lane] = *(const float4*)&U4f[((size_t)b * TSTEPS + lane) * 4];
        int w = lane / 5, s5 = (lane - w * 5) * 6;
        dacW[wv][lane] = (bi[7 + w] >> s5) & 63;
    }
    if (lane < 17) *(uint4*)&Sw[20 * SR + lane * 8] = make_uint4(0, 0, 0, 0);  // zero row 20

    const float* Wx = W1 + (size_t)NI * HID;
    const __bf16* Wb = (const __bf16*)W2T;
    floatx4 acc[2][3];
    for (int a = 0; a < 2; a++) for (int c = 0; c < 3; c++) acc[a][c] = (floatx4){0.f, 0.f, 0.f, 0.f};

    for (int it = 0; it < 16; it++) {
        int j = it * 128 + 2 * lane;
        // phase A loads (all independent, issue together)
        float2 w0  = *(const float2*)&Wx[j];
        float2 w1  = *(const float2*)&Wx[HID + j];
        float2 wdl = *(const float2*)&Wx[46 * HID + j];
        float2 wch = *(const float2*)&Wx[47 * HID + j];
        float2 hb  = *(const float2*)&base[(size_t)b * HID + j];  // incl. b1 + t0 consts
        float2 d0 = {0,0}, d1 = {0,0}, d2 = {0,0}, d3 = {0,0}, d4 = {0,0};
        if (ns > 0) { float2 rn = *(const float2*)&Wx[(size_t)rAn * HID + j], ro = *(const float2*)&Wx[(size_t)rAo * HID + j]; d0.x = rn.x - ro.x; d0.y = rn.y - ro.y; }
        if (ns > 1) { float2 rn = *(const float2*)&Wx[(size_t)rBn * HID + j], ro = *(const float2*)&Wx[(size_t)rBo * HID + j]; d1.x = rn.x - ro.x; d1.y = rn.y - ro.y; }
        if (ns > 2) { float2 rn = *(const float2*)&Wx[(size_t)rCn * HID + j], ro = *(const float2*)&Wx[(size_t)rCo * HID + j]; d2.x = rn.x - ro.x; d2.y = rn.y - ro.y; }
        if (ns > 3) { float2 rn = *(const float2*)&Wx[(size_t)rDn * HID + j], ro = *(const float2*)&Wx[(size_t)rDo * HID + j]; d3.x = rn.x - ro.x; d3.y = rn.y - ro.y; }
        if (ns > 4) { float2 rn = *(const float2*)&Wx[(size_t)rEn * HID + j], ro = *(const float2*)&Wx[(size_t)rEo * HID + j]; d4.x = rn.x - ro.x; d4.y = rn.y - ro.y; }
        float hbs0 = hb.x, hbs1 = hb.y;
#pragma unroll
        for (int t = 0; t < TSTEPS; t++) {
            int sel = (t < 10) ? ((selLo >> (3 * t)) & 7) : ((selHi >> (3 * (t - 10))) & 7);
            if (sel != 7) {  // uniform scalar branch (<=5 taken)
                float2 d = (sel == 0) ? d0 : (sel == 1) ? d1 : (sel == 2) ? d2 : (sel == 3) ? d3 : d4;
                hbs0 += d.x; hbs1 += d.y;
            }
            float4 u = u4s[wv][t];   // broadcast read
            float h0 = fmaf(u.x, w0.x, fmaf(u.y, w1.x, fmaf(u.z, wdl.x, fmaf(u.w, wch.x, hbs0))));
            float h1 = fmaf(u.x, w0.y, fmaf(u.y, w1.y, fmaf(u.z, wdl.y, fmaf(u.w, wch.y, hbs1))));
            float s0 = h0 * __builtin_amdgcn_rcpf(1.f + __expf(-h0));
            float s1 = h1 * __builtin_amdgcn_rcpf(1.f + __expf(-h1));
            union { float f; unsigned u; } v0, v1;
            v0.f = s0; v1.f = s1;
            unsigned pkd = ((v0.u + 0x8000u) >> 16) | ((v1.u + 0x8000u) & 0xFFFF0000u);
            *(unsigned*)&Sw[t * SR + 2 * lane] = pkd;
        }
        // phase B: this wave's K-chunk of 128 (same-wave DS ordering, no barrier)
        int row1 = (l15 < 4) ? 16 + l15 : 20;   // row 20 is the zero row
#pragma unroll
        for (int kc = 0; kc < 4; kc++) {
            int kloc = kc * 32 + q * 8;
            bf16x8 a0 = *(const bf16x8*)&Sw[l15 * SR + kloc];
            bf16x8 a1 = *(const bf16x8*)&Sw[row1 * SR + kloc];
            int kg = it * 128 + kloc;
            bf16x8 b0  = *(const bf16x8*)&Wb[(size_t)l15 * HID + kg];
            bf16x8 b1v = *(const bf16x8*)&Wb[(size_t)(16 + l15) * HID + kg];
            bf16x8 b2v = *(const bf16x8*)&Wb[(size_t)(32 + l15) * HID + kg];
            acc[0][0] = __builtin_amdgcn_mfma_f32_16x16x32_bf16(a0, b0,  acc[0][0], 0, 0, 0);
            acc[0][1] = __builtin_amdgcn_mfma_f32_16x16x32_bf16(a0, b1v, acc[0][1], 0, 0, 0);
            acc[0][2] = __builtin_amdgcn_mfma_f32_16x16x32_bf16(a0, b2v, acc[0][2], 0, 0, 0);
            acc[1][0] = __builtin_amdgcn_mfma_f32_16x16x32_bf16(a1, b0,  acc[1][0], 0, 0, 0);
            acc[1][1] = __builtin_amdgcn_mfma_f32_16x16x32_bf16(a1, b1v, acc[1][1], 0, 0, 0);
            acc[1][2] = __builtin_amdgcn_mfma_f32_16x16x32_bf16(a1, b2v, acc[1][2], 0, 0, 0);
        }
    }

    // --- in-register CE (classes on l15 x nt; t = mt*16 + q*4 + r) ---
    float bb0 = b2[l15];
    float bb1 = b2[16 + l15];
    float bb2 = -1e30f;                      // pad classes 45..47 -> -inf
    if (l15 < 13) bb2 = b2[32 + l15];
    float ceTot = 0.f;
#pragma unroll
    for (int mt = 0; mt < 2; mt++)
#pragma unroll
        for (int r = 0; r < 4; r++) {
            int t = mt * 16 + q * 4 + r;     // per-lane
            float l0 = acc[mt][0][r] + bb0;
            float l1 = acc[mt][1][r] + bb1;
            float l2 = acc[mt][2][r] + bb2;
            int dac = dacW[wv][t < TSTEPS ? t : 0];
            float mx = fmaxf(fmaxf(l0, l1), l2);
            float tl = -1e30f;
            tl = (l15      == dac) ? l0 : tl;
            tl = (16 + l15 == dac) ? l1 : tl;
            tl = (32 + l15 == dac) ? l2 : tl;
#pragma unroll
            for (int m = 1; m <= 8; m <<= 1) {
                mx = fmaxf(mx, __shfl_xor(mx, m));
                tl = fmaxf(tl, __shfl_xor(tl, m));
            }
            float s = __expf(l0 - mx) + __expf(l1 - mx) + __expf(l2 - mx);
#pragma unroll
            for (int m = 1; m <= 8; m <<= 1) s += __shfl_xor(s, m);
            float ce = -(tl - mx - __logf(s));
            ceTot += (t < nAlive) ? ce : 0.f;
        }
    ceTot += __shfl_xor(ceTot, 16);
    ceTot += __shfl_xor(ceTot, 32);
    if (lane == 0) loss_out[b] = ceTot / (float)nAlive;
}

// ---------------------------------------------------------------------------
// Kernel 4: deterministic final reduction over 4096 per-b losses
// ---------------------------------------------------------------------------
__global__ void reduce_loss(const float* __restrict__ loss, float* __restrict__ out) {
    int tid = threadIdx.x;  // 256
    float s = 0.f;
    for (int i = tid; i < BATCH; i += 256) s += loss[i];
    for (int off = 32; off > 0; off >>= 1) s += __shfl_down(s, off, 64);
    __shared__ float wsum[4];
    if ((tid & 63) == 0) wsum[tid >> 6] = s;
    __syncthreads();
    if (tid == 0) out[0] = (wsum[0] + wsum[1] + wsum[2] + wsum[3]) * (1.0f / (float)BATCH);
}

// ---------------------------------------------------------------------------
extern "C" void kernel_launch(void* const* d_in, const int* in_sizes, int n_in,
                              void* d_out, int out_size, void* d_ws, size_t ws_size,
                              hipStream_t stream) {
    const float* fc_input = (const float*)d_in[0];
    const float* camera   = (const float*)d_in[1];
    const int*   fb       = (const int*)d_in[2];
    const int*   lr       = (const int*)d_in[3];
    const int*   jp       = (const int*)d_in[4];
    const int*   ss       = (const int*)d_in[5];
    const int*   at       = (const int*)d_in[6];
    const float* W1       = (const float*)d_in[7];
    const float* b1       = (const float*)d_in[8];
    const float* W2       = (const float*)d_in[9];
    const float* b2       = (const float*)d_in[10];
    float* out = (float*)d_out;

    char* ws = (char*)d_ws;
    unsigned short* Wt   = (unsigned short*)(ws);                       //  4,194,304 B
    float*          baseB= (float*)(ws + 4194304);                      // 33,554,432 B
    float*          U4f  = (float*)(ws + 37748736);                     //  1,310,720 B
    int*            BI   = (int*)(ws + 39059456);                       //    196,608 B
    float*          lossB= (float*)(ws + 39256064);                     //     16,384 B
    unsigned short* W2T  = (unsigned short*)(ws + 39272448);            //    196,608 B

    prep_kernel<<<2048 + 8 + 16, 256, 0, stream>>>(W1, Wt, W2, W2T,
                                                   camera, fb, lr, jp, ss, at, U4f, BI);
    gemm_base<<<dim3(HID / 128, BATCH / 128), 256, 0, stream>>>(fc_input, Wt, W1, b1, baseB);
    fused_mlp<<<BATCH / 4, 256, 0, stream>>>(baseB, W1, W2T, b2, U4f, BI, lossB);
    reduce_loss<<<1, 256, 0, stream>>>(lossB, out);
}

// Round 7
// 562.706 us; speedup vs baseline: 1.1168x; 1.1168x over previous
//
#include <hip/hip_runtime.h>

// Problem constants
#define BATCH 4096
#define NI 1024
#define HID 2048
#define TSTEPS 20
#define NA 45
#define SR 136     // fused S row stride in bf16 elems (128 + 8 pad)
#define SWROWS 21  // 20 t-rows + 1 zero row for masked A-frag reads

typedef __bf16 bf16x8 __attribute__((ext_vector_type(8)));
typedef float floatx4 __attribute__((ext_vector_type(4)));

__device__ __forceinline__ unsigned short f2bf(float x) {
    union { float f; unsigned int u; } un; un.f = x;
    unsigned int r = un.u + 0x7FFFu + ((un.u >> 16) & 1u);
    return (unsigned short)(r >> 16);
}

__device__ __forceinline__ ushort4 cvt4(float4 v) {
    ushort4 o;
    o.x = f2bf(v.x); o.y = f2bf(v.y); o.z = f2bf(v.z); o.w = f2bf(v.w);
    return o;
}

// ---------------------------------------------------------------------------
// Kernel 1 (merged prep): transpose_w1 (blocks [0,2048)), convert_w2
// (blocks [2048,2056)), scan (blocks [2056,2072)).
// scan: exact fp32 replication of the 20-step state machine. Emits per-b:
//   U4[b][20] float4 = (ac0, ac1, delta-0.0625, chosen)  [absolute state]
//   BI[b][12] ints: 0 selLo, 1 selHi (3b/t swap-slot or 7), 2 cAB, 3 cCD,
//   4 cE (packed (old<<8)|new cols), 5 nAlive (alive is monotone!), 6 ns,
//   7..10 dacPk (6b/dac, 5 per int), 11 pad.
// x-col offsets of extras: ac0=0 ac1=1 fb=2..4 lr=5..7 jp=8..9 ss=10..13
// at=14..45 delta=46 chosen=47.
// ---------------------------------------------------------------------------
__global__ void prep_kernel(const float* __restrict__ W1, unsigned short* __restrict__ Wt,
                            const float* __restrict__ W2, unsigned short* __restrict__ W2T,
                            const float* __restrict__ camera,
                            const int* __restrict__ fb_in, const int* __restrict__ lr_in,
                            const int* __restrict__ jp_in, const int* __restrict__ ss_in,
                            const int* __restrict__ at_in,
                            float* __restrict__ U4f, int* __restrict__ BI) {
    __shared__ float tile[32][33];
    int bid = blockIdx.x, tid = threadIdx.x;
    if (bid < 2048) {
        int k0 = (bid & 31) * 32, n0 = (bid >> 5) * 32;
        int tx = tid & 31, ty = tid >> 5;  // (32, 8)
        for (int i = 0; i < 4; i++)
            tile[ty + 8 * i][tx] = W1[(size_t)(k0 + ty + 8 * i) * HID + n0 + tx];
        __syncthreads();
        for (int i = 0; i < 4; i++) {
            int n = ty + 8 * i;
            Wt[(size_t)(n0 + n) * NI + k0 + tx] = f2bf(tile[tx][n]);
        }
    } else if (bid < 2056) {
        int k = (bid - 2048) * 256 + tid;  // 0..2047
        for (int n = 0; n < 48; n++)
            W2T[(size_t)n * HID + k] = (n < NA) ? f2bf(W2[(size_t)k * NA + n]) : (unsigned short)0;
    } else {
        int b = (bid - 2056) * 256 + tid;
        if (b >= BATCH) return;
        float cam0 = camera[2 * b], cam1 = camera[2 * b + 1];
        int afb = fb_in[b], alr = lr_in[b], ajp = jp_in[b], ass = ss_in[b], aat = at_in[b];
        float ac0 = 0.f, ac1 = 0.f, delta = 0.0625f;  // MIN_DELTA = 0.5/8
        int rfb = 0, rlr = 0, rjp = 0, rss = 0, rat = 0;
        bool chosen = false, commited = false;
        int cam_steps = 0;
        int chgPending = -1;
        bool camzero = (fabsf(cam0) < 1e-5f) && (fabsf(cam1) < 1e-5f);
        int ns = 0, selLo = 0, selHi = 0, nAlive = 0;
        int swapC[5] = {0, 0, 0, 0, 0};
        int dacPk[4] = {0, 0, 0, 0};
#pragma unroll
        for (int t = 0; t < TSTEPS; t++) {
            // entering step t: apply pending swap to schedule
            int sel = 7;
            if (chgPending >= 0) { swapC[ns] = chgPending; sel = ns; ns++; chgPending = -1; }
            if (t < 10) selLo |= sel << (3 * t); else selHi |= sel << (3 * (t - 10));
            ((float4*)U4f)[b * TSTEPS + t] =
                make_float4(ac0, ac1, delta - 0.0625f, chosen ? 1.f : 0.f);
            nAlive += commited ? 0 : 1;
            bool commit = (camzero || cam_steps >= 6) &&
                          rfb == afb && rlr == alr && rjp == ajp && rss == ass && rat == aat;
            int dac = 0; bool modified = commit;
            if (!modified && rfb != afb) { dac = (afb == 0 ? rfb - 1 + 6  : afb - 1 + 6 ); chgPending = ((2  + rfb) << 8) | (2  + afb); rfb = afb; modified = true; }
            if (!modified && rlr != alr) { dac = (alr == 0 ? rlr - 1 + 8  : alr - 1 + 8 ); chgPending = ((5  + rlr) << 8) | (5  + alr); rlr = alr; modified = true; }
            if (!modified && rjp != ajp) { dac = (ajp == 0 ? rjp - 1 + 10 : ajp - 1 + 10); chgPending = ((8  + rjp) << 8) | (8  + ajp); rjp = ajp; modified = true; }
            if (!modified && rss != ass) { dac = (ass == 0 ? rss - 1 + 11 : ass - 1 + 11); chgPending = ((10 + rss) << 8) | (10 + ass); rss = ass; modified = true; }
            if (!modified && rat != aat) { dac = (aat == 0 ? rat - 1 + 14 : aat - 1 + 14); chgPending = ((14 + rat) << 8) | (14 + aat); rat = aat; modified = true; }
            // NOTE: reference compares BOTH cam0 and cam1 against ac0 (as-is)
            if (!modified && !chosen &&
                (fabsf(cam0 - ac0) > delta * 2.f || fabsf(cam1 - ac0) > delta * 2.f)) {
                dac = 5; delta = fminf(delta * 2.f, 0.5f); modified = true;
            }
            if (!modified) {
                bool incX = cam0 >= ac0, incY = cam1 >= ac1;
                dac = 1 + (incX ? 1 : 0) + (incY ? 2 : 0);
                ac0 += incX ? delta : -delta;
                ac1 += incY ? delta : -delta;
                delta *= 0.5f;
                chosen = true;
                cam_steps++;
            }
            commited = commited || commit;
            dacPk[t / 5] |= dac << (6 * (t % 5));
        }
        int* o = BI + b * 12;
        o[0] = selLo; o[1] = selHi;
        o[2] = swapC[0] | (swapC[1] << 16);
        o[3] = swapC[2] | (swapC[3] << 16);
        o[4] = swapC[4];
        o[5] = nAlive; o[6] = ns;
        o[7] = dacPk[0]; o[8] = dacPk[1]; o[9] = dacPk[2]; o[10] = dacPk[3];
        o[11] = 0;
    }
}

// ---------------------------------------------------------------------------
// Kernel 2: base[4096][2048] = fc_input(fp32, converted in-register) @
// W1[:1024] (bf16 MFMA). Epilogue folds t=0 constants: + b1 + initial
// one-hot rows (2,5,8,10,14) + 0.0625*w_delta.
// ---------------------------------------------------------------------------
__global__ __launch_bounds__(256) void gemm_base(const float* __restrict__ A,
                                                 const unsigned short* __restrict__ Wt,
                                                 const float* __restrict__ W1,
                                                 const float* __restrict__ b1,
                                                 float* __restrict__ C) {
    __shared__ __align__(16) __bf16 At[128 * 32];
    __shared__ __align__(16) __bf16 Bt[128 * 32];
    int bn = blockIdx.x, bm = blockIdx.y;
    int m0 = bm * 128, n0 = bn * 128;
    int tid = threadIdx.x;
    int wave = tid >> 6, lane = tid & 63;
    int wr = wave >> 1, wc = wave & 1;
    int l15 = lane & 15, q = lane >> 4;
    floatx4 acc[4][4];
    for (int a = 0; a < 4; a++) for (int c = 0; c < 4; c++) acc[a][c] = (floatx4){0.f, 0.f, 0.f, 0.f};
    int arow = tid >> 1, aseg = (tid & 1) * 16;
    for (int k0 = 0; k0 < NI; k0 += 32) {
        __syncthreads();
#pragma unroll
        for (int i = 0; i < 2; i++) {
            int c = i * 256 + tid;
            int row = c >> 2, quarter = c & 3;
            const unsigned short* gB = &Wt[(size_t)(n0 + row) * NI + k0 + quarter * 8];
            __builtin_amdgcn_global_load_lds(
                (const __attribute__((address_space(1))) unsigned int*)gB,
                (__attribute__((address_space(3))) unsigned int*)&Bt[c * 8], 16, 0, 0);
        }
        const float* ga = &A[(size_t)(m0 + arow) * NI + k0 + aseg];
        float4 f0 = *(const float4*)&ga[0];
        float4 f1 = *(const float4*)&ga[4];
        float4 f2 = *(const float4*)&ga[8];
        float4 f3 = *(const float4*)&ga[12];
        union { ushort4 s4[4]; uint4 v[2]; } pk;
        pk.s4[0] = cvt4(f0); pk.s4[1] = cvt4(f1); pk.s4[2] = cvt4(f2); pk.s4[3] = cvt4(f3);
        *(uint4*)&At[arow * 32 + aseg]     = pk.v[0];
        *(uint4*)&At[arow * 32 + aseg + 8] = pk.v[1];
        __syncthreads();
        bf16x8 af[4], bf[4];
        for (int mr = 0; mr < 4; mr++)
            af[mr] = *(const bf16x8*)&At[(wr * 64 + mr * 16 + l15) * 32 + q * 8];
        for (int nc = 0; nc < 4; nc++)
            bf[nc] = *(const bf16x8*)&Bt[(wc * 64 + nc * 16 + l15) * 32 + q * 8];
        for (int mr = 0; mr < 4; mr++)
            for (int nc = 0; nc < 4; nc++)
                acc[mr][nc] = __builtin_amdgcn_mfma_f32_16x16x32_bf16(af[mr], bf[nc], acc[mr][nc], 0, 0, 0);
    }
    for (int nc = 0; nc < 4; nc++) {
        int col = n0 + wc * 64 + nc * 16 + l15;
        const float* We = W1 + (size_t)NI * HID + col;
        float cv = b1[col] + We[2 * HID] + We[5 * HID] + We[8 * HID] + We[10 * HID]
                 + We[14 * HID] + 0.0625f * We[46 * HID];
        for (int mr = 0; mr < 4; mr++)
            for (int r = 0; r < 4; r++) {
                int row = m0 + wr * 64 + mr * 16 + q * 4 + r;
                C[(size_t)row * HID + col] = acc[mr][nc][r] + cv;
            }
    }
}

// ---------------------------------------------------------------------------
// Kernel 3: BARRIER-FREE fused MLP + CE. One WAVE per b (4 waves/block),
// zero __syncthreads — all LDS use is wave-private (DS ops are in-order
// within a wave). launch_bounds(256,4): 128-VGPR cap — R6's (256,5) capped
// at ~96 and spilled the ~20 live float2s, causing 1.4 GB of scratch
// round-trips (WRITE_SIZE 166 MB). Live need ~70-90 regs fits in 128.
// ---------------------------------------------------------------------------
__global__ __launch_bounds__(256, 4) void fused_mlp(const float* __restrict__ base,
                                                    const float* __restrict__ W1,
                                                    const unsigned short* __restrict__ W2T,
                                                    const float* __restrict__ b2,
                                                    const float* __restrict__ U4f,
                                                    const int* __restrict__ BI,
                                                    float* __restrict__ loss_out) {
    __shared__ __align__(16) __bf16 S[4 * SWROWS * SR];  // 22,848 B (wave-private slabs)
    __shared__ __align__(16) float4 u4s[4][TSTEPS];      //  1,280 B
    __shared__ int dacW[4][TSTEPS];                      //    320 B

    int tid = threadIdx.x;
    int wv = tid >> 6, lane = tid & 63, l15 = lane & 15, q = lane >> 4;
    int b = blockIdx.x * 4 + wv;
    __bf16* Sw = S + wv * (SWROWS * SR);

    // --- per-b uniform scalars ---
    const int* bi = BI + b * 12;
    int selLo  = __builtin_amdgcn_readfirstlane(bi[0]);
    int selHi  = __builtin_amdgcn_readfirstlane(bi[1]);
    int cAB    = __builtin_amdgcn_readfirstlane(bi[2]);
    int cCD    = __builtin_amdgcn_readfirstlane(bi[3]);
    int cE     = __builtin_amdgcn_readfirstlane(bi[4]);
    int nAlive = __builtin_amdgcn_readfirstlane(bi[5]);
    int ns     = __builtin_amdgcn_readfirstlane(bi[6]);
    int rAn = cAB & 255,         rAo = (cAB >> 8) & 255;
    int rBn = (cAB >> 16) & 255, rBo = (cAB >> 24) & 255;
    int rCn = cCD & 255,         rCo = (cCD >> 8) & 255;
    int rDn = (cCD >> 16) & 255, rDo = (cCD >> 24) & 255;
    int rEn = cE & 255,          rEo = (cE >> 8) & 255;

    // --- wave-private LDS setup (no barrier: same-wave DS ordering) ---
    if (lane < TSTEPS) {
        u4s[wv][lane] = *(const float4*)&U4f[((size_t)b * TSTEPS + lane) * 4];
        int w = lane / 5, s5 = (lane - w * 5) * 6;
        dacW[wv][lane] = (bi[7 + w] >> s5) & 63;
    }
    if (lane < 17) *(uint4*)&Sw[20 * SR + lane * 8] = make_uint4(0, 0, 0, 0);  // zero row 20

    const float* Wx = W1 + (size_t)NI * HID;
    const __bf16* Wb = (const __bf16*)W2T;
    floatx4 acc[2][3];
    for (int a = 0; a < 2; a++) for (int c = 0; c < 3; c++) acc[a][c] = (floatx4){0.f, 0.f, 0.f, 0.f};

    for (int it = 0; it < 16; it++) {
        int j = it * 128 + 2 * lane;
        // phase A loads (all independent, issue together)
        float2 w0  = *(const float2*)&Wx[j];
        float2 w1  = *(const float2*)&Wx[HID + j];
        float2 wdl = *(const float2*)&Wx[46 * HID + j];
        float2 wch = *(const float2*)&Wx[47 * HID + j];
        float2 hb  = *(const float2*)&base[(size_t)b * HID + j];  // incl. b1 + t0 consts
        float2 d0 = {0,0}, d1 = {0,0}, d2 = {0,0}, d3 = {0,0}, d4 = {0,0};
        if (ns > 0) { float2 rn = *(const float2*)&Wx[(size_t)rAn * HID + j], ro = *(const float2*)&Wx[(size_t)rAo * HID + j]; d0.x = rn.x - ro.x; d0.y = rn.y - ro.y; }
        if (ns > 1) { float2 rn = *(const float2*)&Wx[(size_t)rBn * HID + j], ro = *(const float2*)&Wx[(size_t)rBo * HID + j]; d1.x = rn.x - ro.x; d1.y = rn.y - ro.y; }
        if (ns > 2) { float2 rn = *(const float2*)&Wx[(size_t)rCn * HID + j], ro = *(const float2*)&Wx[(size_t)rCo * HID + j]; d2.x = rn.x - ro.x; d2.y = rn.y - ro.y; }
        if (ns > 3) { float2 rn = *(const float2*)&Wx[(size_t)rDn * HID + j], ro = *(const float2*)&Wx[(size_t)rDo * HID + j]; d3.x = rn.x - ro.x; d3.y = rn.y - ro.y; }
        if (ns > 4) { float2 rn = *(const float2*)&Wx[(size_t)rEn * HID + j], ro = *(const float2*)&Wx[(size_t)rEo * HID + j]; d4.x = rn.x - ro.x; d4.y = rn.y - ro.y; }
        float hbs0 = hb.x, hbs1 = hb.y;
#pragma unroll
        for (int t = 0; t < TSTEPS; t++) {
            int sel = (t < 10) ? ((selLo >> (3 * t)) & 7) : ((selHi >> (3 * (t - 10))) & 7);
            if (sel != 7) {  // uniform scalar branch (<=5 taken)
                float2 d = (sel == 0) ? d0 : (sel == 1) ? d1 : (sel == 2) ? d2 : (sel == 3) ? d3 : d4;
                hbs0 += d.x; hbs1 += d.y;
            }
            float4 u = u4s[wv][t];   // broadcast read
            float h0 = fmaf(u.x, w0.x, fmaf(u.y, w1.x, fmaf(u.z, wdl.x, fmaf(u.w, wch.x, hbs0))));
            float h1 = fmaf(u.x, w0.y, fmaf(u.y, w1.y, fmaf(u.z, wdl.y, fmaf(u.w, wch.y, hbs1))));
            float s0 = h0 * __builtin_amdgcn_rcpf(1.f + __expf(-h0));
            float s1 = h1 * __builtin_amdgcn_rcpf(1.f + __expf(-h1));
            union { float f; unsigned u; } v0, v1;
            v0.f = s0; v1.f = s1;
            unsigned pkd = ((v0.u + 0x8000u) >> 16) | ((v1.u + 0x8000u) & 0xFFFF0000u);
            *(unsigned*)&Sw[t * SR + 2 * lane] = pkd;
        }
        // phase B: this wave's K-chunk of 128 (same-wave DS ordering, no barrier)
        int row1 = (l15 < 4) ? 16 + l15 : 20;   // row 20 is the zero row
#pragma unroll
        for (int kc = 0; kc < 4; kc++) {
            int kloc = kc * 32 + q * 8;
            bf16x8 a0 = *(const bf16x8*)&Sw[l15 * SR + kloc];
            bf16x8 a1 = *(const bf16x8*)&Sw[row1 * SR + kloc];
            int kg = it * 128 + kloc;
            bf16x8 b0  = *(const bf16x8*)&Wb[(size_t)l15 * HID + kg];
            bf16x8 b1v = *(const bf16x8*)&Wb[(size_t)(16 + l15) * HID + kg];
            bf16x8 b2v = *(const bf16x8*)&Wb[(size_t)(32 + l15) * HID + kg];
            acc[0][0] = __builtin_amdgcn_mfma_f32_16x16x32_bf16(a0, b0,  acc[0][0], 0, 0, 0);
            acc[0][1] = __builtin_amdgcn_mfma_f32_16x16x32_bf16(a0, b1v, acc[0][1], 0, 0, 0);
            acc[0][2] = __builtin_amdgcn_mfma_f32_16x16x32_bf16(a0, b2v, acc[0][2], 0, 0, 0);
            acc[1][0] = __builtin_amdgcn_mfma_f32_16x16x32_bf16(a1, b0,  acc[1][0], 0, 0, 0);
            acc[1][1] = __builtin_amdgcn_mfma_f32_16x16x32_bf16(a1, b1v, acc[1][1], 0, 0, 0);
            acc[1][2] = __builtin_amdgcn_mfma_f32_16x16x32_bf16(a1, b2v, acc[1][2], 0, 0, 0);
        }
    }

    // --- in-register CE (classes on l15 x nt; t = mt*16 + q*4 + r) ---
    float bb0 = b2[l15];
    float bb1 = b2[16 + l15];
    float bb2 = -1e30f;                      // pad classes 45..47 -> -inf
    if (l15 < 13) bb2 = b2[32 + l15];
    float ceTot = 0.f;
#pragma unroll
    for (int mt = 0; mt < 2; mt++)
#pragma unroll
        for (int r = 0; r < 4; r++) {
            int t = mt * 16 + q * 4 + r;     // per-lane
            float l0 = acc[mt][0][r] + bb0;
            float l1 = acc[mt][1][r] + bb1;
            float l2 = acc[mt][2][r] + bb2;
            int dac = dacW[wv][t < TSTEPS ? t : 0];
            float mx = fmaxf(fmaxf(l0, l1), l2);
            float tl = -1e30f;
            tl = (l15      == dac) ? l0 : tl;
            tl = (16 + l15 == dac) ? l1 : tl;
            tl = (32 + l15 == dac) ? l2 : tl;
#pragma unroll
            for (int m = 1; m <= 8; m <<= 1) {
                mx = fmaxf(mx, __shfl_xor(mx, m));
                tl = fmaxf(tl, __shfl_xor(tl, m));
            }
            float s = __expf(l0 - mx) + __expf(l1 - mx) + __expf(l2 - mx);
#pragma unroll
            for (int m = 1; m <= 8; m <<= 1) s += __shfl_xor(s, m);
            float ce = -(tl - mx - __logf(s));
            ceTot += (t < nAlive) ? ce : 0.f;
        }
    ceTot += __shfl_xor(ceTot, 16);
    ceTot += __shfl_xor(ceTot, 32);
    if (lane == 0) loss_out[b] = ceTot / (float)nAlive;
}

// ---------------------------------------------------------------------------
// Kernel 4: deterministic final reduction over 4096 per-b losses
// ---------------------------------------------------------------------------
__global__ void reduce_loss(const float* __restrict__ loss, float* __restrict__ out) {
    int tid = threadIdx.x;  // 256
    float s = 0.f;
    for (int i = tid; i < BATCH; i += 256) s += loss[i];
    for (int off = 32; off > 0; off >>= 1) s += __shfl_down(s, off, 64);
    __shared__ float wsum[4];
    if ((tid & 63) == 0) wsum[tid >> 6] = s;
    __syncthreads();
    if (tid == 0) out[0] = (wsum[0] + wsum[1] + wsum[2] + wsum[3]) * (1.0f / (float)BATCH);
}

// ---------------------------------------------------------------------------
extern "C" void kernel_launch(void* const* d_in, const int* in_sizes, int n_in,
                              void* d_out, int out_size, void* d_ws, size_t ws_size,
                              hipStream_t stream) {
    const float* fc_input = (const float*)d_in[0];
    const float* camera   = (const float*)d_in[1];
    const int*   fb       = (const int*)d_in[2];
    const int*   lr       = (const int*)d_in[3];
    const int*   jp       = (const int*)d_in[4];
    const int*   ss       = (const int*)d_in[5];
    const int*   at       = (const int*)d_in[6];
    const float* W1       = (const float*)d_in[7];
    const float* b1       = (const float*)d_in[8];
    const float* W2       = (const float*)d_in[9];
    const float* b2       = (const float*)d_in[10];
    float* out = (float*)d_out;

    char* ws = (char*)d_ws;
    unsigned short* Wt   = (unsigned short*)(ws);                       //  4,194,304 B
    float*          baseB= (float*)(ws + 4194304);                      // 33,554,432 B
    float*          U4f  = (float*)(ws + 37748736);                     //  1,310,720 B
    int*            BI   = (int*)(ws + 39059456);                       //    196,608 B
    float*          lossB= (float*)(ws + 39256064);                     //     16,384 B
    unsigned short* W2T  = (unsigned short*)(ws + 39272448);            //    196,608 B

    prep_kernel<<<2048 + 8 + 16, 256, 0, stream>>>(W1, Wt, W2, W2T,
                                                   camera, fb, lr, jp, ss, at, U4f, BI);
    gemm_base<<<dim3(HID / 128, BATCH / 128), 256, 0, stream>>>(fc_input, Wt, W1, b1, baseB);
    fused_mlp<<<BATCH / 4, 256, 0, stream>>>(baseB, W1, W2T, b2, U4f, BI, lossB);
    reduce_loss<<<1, 256, 0, stream>>>(lossB, out);
}

// Round 8
// 307.620 us; speedup vs baseline: 2.0429x; 1.8292x over previous
//
#include <hip/hip_runtime.h>

// Problem constants
#define BATCH 4096
#define NI 1024
#define HID 2048
#define TSTEPS 20
#define NA 45
#define SR 136     // fused S row stride in bf16 elems (128 + 8 pad)
#define SWROWS 21  // 20 t-rows + 1 zero row for masked A-frag reads

typedef __bf16 bf16x8 __attribute__((ext_vector_type(8)));
typedef float floatx4 __attribute__((ext_vector_type(4)));

__device__ __forceinline__ unsigned short f2bf(float x) {
    union { float f; unsigned int u; } un; un.f = x;
    unsigned int r = un.u + 0x7FFFu + ((un.u >> 16) & 1u);
    return (unsigned short)(r >> 16);
}

__device__ __forceinline__ ushort4 cvt4(float4 v) {
    ushort4 o;
    o.x = f2bf(v.x); o.y = f2bf(v.y); o.z = f2bf(v.z); o.w = f2bf(v.w);
    return o;
}

// ---------------------------------------------------------------------------
// Kernel 1 (merged prep): transpose_w1 (blocks [0,2048)), convert_w2
// (blocks [2048,2056)), scan (blocks [2056,2072)).
// scan: exact fp32 replication of the 20-step state machine. Emits per-b:
//   U4[b][20] float4 = (ac0, ac1, delta-0.0625, chosen)  [absolute state]
//   BI[b][12] ints: 0 selLo, 1 selHi (3b/t swap-slot or 7), 2 cAB, 3 cCD,
//   4 cE (packed (old<<8)|new cols), 5 nAlive (alive is monotone!), 6 ns,
//   7..10 dacPk (6b/dac, 5 per int), 11 pad.
// x-col offsets of extras: ac0=0 ac1=1 fb=2..4 lr=5..7 jp=8..9 ss=10..13
// at=14..45 delta=46 chosen=47.
// ---------------------------------------------------------------------------
__global__ void prep_kernel(const float* __restrict__ W1, unsigned short* __restrict__ Wt,
                            const float* __restrict__ W2, unsigned short* __restrict__ W2T,
                            const float* __restrict__ camera,
                            const int* __restrict__ fb_in, const int* __restrict__ lr_in,
                            const int* __restrict__ jp_in, const int* __restrict__ ss_in,
                            const int* __restrict__ at_in,
                            float* __restrict__ U4f, int* __restrict__ BI) {
    __shared__ float tile[32][33];
    int bid = blockIdx.x, tid = threadIdx.x;
    if (bid < 2048) {
        int k0 = (bid & 31) * 32, n0 = (bid >> 5) * 32;
        int tx = tid & 31, ty = tid >> 5;  // (32, 8)
        for (int i = 0; i < 4; i++)
            tile[ty + 8 * i][tx] = W1[(size_t)(k0 + ty + 8 * i) * HID + n0 + tx];
        __syncthreads();
        for (int i = 0; i < 4; i++) {
            int n = ty + 8 * i;
            Wt[(size_t)(n0 + n) * NI + k0 + tx] = f2bf(tile[tx][n]);
        }
    } else if (bid < 2056) {
        int k = (bid - 2048) * 256 + tid;  // 0..2047
        for (int n = 0; n < 48; n++)
            W2T[(size_t)n * HID + k] = (n < NA) ? f2bf(W2[(size_t)k * NA + n]) : (unsigned short)0;
    } else {
        int b = (bid - 2056) * 256 + tid;
        if (b >= BATCH) return;
        float cam0 = camera[2 * b], cam1 = camera[2 * b + 1];
        int afb = fb_in[b], alr = lr_in[b], ajp = jp_in[b], ass = ss_in[b], aat = at_in[b];
        float ac0 = 0.f, ac1 = 0.f, delta = 0.0625f;  // MIN_DELTA = 0.5/8
        int rfb = 0, rlr = 0, rjp = 0, rss = 0, rat = 0;
        bool chosen = false, commited = false;
        int cam_steps = 0;
        int chgPending = -1;
        bool camzero = (fabsf(cam0) < 1e-5f) && (fabsf(cam1) < 1e-5f);
        int ns = 0, selLo = 0, selHi = 0, nAlive = 0;
        int swapC[5] = {0, 0, 0, 0, 0};
        int dacPk[4] = {0, 0, 0, 0};
#pragma unroll
        for (int t = 0; t < TSTEPS; t++) {
            // entering step t: apply pending swap to schedule
            int sel = 7;
            if (chgPending >= 0) { swapC[ns] = chgPending; sel = ns; ns++; chgPending = -1; }
            if (t < 10) selLo |= sel << (3 * t); else selHi |= sel << (3 * (t - 10));
            ((float4*)U4f)[b * TSTEPS + t] =
                make_float4(ac0, ac1, delta - 0.0625f, chosen ? 1.f : 0.f);
            nAlive += commited ? 0 : 1;
            bool commit = (camzero || cam_steps >= 6) &&
                          rfb == afb && rlr == alr && rjp == ajp && rss == ass && rat == aat;
            int dac = 0; bool modified = commit;
            if (!modified && rfb != afb) { dac = (afb == 0 ? rfb - 1 + 6  : afb - 1 + 6 ); chgPending = ((2  + rfb) << 8) | (2  + afb); rfb = afb; modified = true; }
            if (!modified && rlr != alr) { dac = (alr == 0 ? rlr - 1 + 8  : alr - 1 + 8 ); chgPending = ((5  + rlr) << 8) | (5  + alr); rlr = alr; modified = true; }
            if (!modified && rjp != ajp) { dac = (ajp == 0 ? rjp - 1 + 10 : ajp - 1 + 10); chgPending = ((8  + rjp) << 8) | (8  + ajp); rjp = ajp; modified = true; }
            if (!modified && rss != ass) { dac = (ass == 0 ? rss - 1 + 11 : ass - 1 + 11); chgPending = ((10 + rss) << 8) | (10 + ass); rss = ass; modified = true; }
            if (!modified && rat != aat) { dac = (aat == 0 ? rat - 1 + 14 : aat - 1 + 14); chgPending = ((14 + rat) << 8) | (14 + aat); rat = aat; modified = true; }
            // NOTE: reference compares BOTH cam0 and cam1 against ac0 (as-is)
            if (!modified && !chosen &&
                (fabsf(cam0 - ac0) > delta * 2.f || fabsf(cam1 - ac0) > delta * 2.f)) {
                dac = 5; delta = fminf(delta * 2.f, 0.5f); modified = true;
            }
            if (!modified) {
                bool incX = cam0 >= ac0, incY = cam1 >= ac1;
                dac = 1 + (incX ? 1 : 0) + (incY ? 2 : 0);
                ac0 += incX ? delta : -delta;
                ac1 += incY ? delta : -delta;
                delta *= 0.5f;
                chosen = true;
                cam_steps++;
            }
            commited = commited || commit;
            dacPk[t / 5] |= dac << (6 * (t % 5));
        }
        int* o = BI + b * 12;
        o[0] = selLo; o[1] = selHi;
        o[2] = swapC[0] | (swapC[1] << 16);
        o[3] = swapC[2] | (swapC[3] << 16);
        o[4] = swapC[4];
        o[5] = nAlive; o[6] = ns;
        o[7] = dacPk[0]; o[8] = dacPk[1]; o[9] = dacPk[2]; o[10] = dacPk[3];
        o[11] = 0;
    }
}

// ---------------------------------------------------------------------------
// Kernel 2: base[4096][2048] = fc_input(fp32, converted in-register) @
// W1[:1024] (bf16 MFMA). Epilogue folds t=0 constants: + b1 + initial
// one-hot rows (2,5,8,10,14) + 0.0625*w_delta.
// ---------------------------------------------------------------------------
__global__ __launch_bounds__(256) void gemm_base(const float* __restrict__ A,
                                                 const unsigned short* __restrict__ Wt,
                                                 const float* __restrict__ W1,
                                                 const float* __restrict__ b1,
                                                 float* __restrict__ C) {
    __shared__ __align__(16) __bf16 At[128 * 32];
    __shared__ __align__(16) __bf16 Bt[128 * 32];
    int bn = blockIdx.x, bm = blockIdx.y;
    int m0 = bm * 128, n0 = bn * 128;
    int tid = threadIdx.x;
    int wave = tid >> 6, lane = tid & 63;
    int wr = wave >> 1, wc = wave & 1;
    int l15 = lane & 15, q = lane >> 4;
    floatx4 acc[4][4];
    for (int a = 0; a < 4; a++) for (int c = 0; c < 4; c++) acc[a][c] = (floatx4){0.f, 0.f, 0.f, 0.f};
    int arow = tid >> 1, aseg = (tid & 1) * 16;
    for (int k0 = 0; k0 < NI; k0 += 32) {
        __syncthreads();
#pragma unroll
        for (int i = 0; i < 2; i++) {
            int c = i * 256 + tid;
            int row = c >> 2, quarter = c & 3;
            const unsigned short* gB = &Wt[(size_t)(n0 + row) * NI + k0 + quarter * 8];
            __builtin_amdgcn_global_load_lds(
                (const __attribute__((address_space(1))) unsigned int*)gB,
                (__attribute__((address_space(3))) unsigned int*)&Bt[c * 8], 16, 0, 0);
        }
        const float* ga = &A[(size_t)(m0 + arow) * NI + k0 + aseg];
        float4 f0 = *(const float4*)&ga[0];
        float4 f1 = *(const float4*)&ga[4];
        float4 f2 = *(const float4*)&ga[8];
        float4 f3 = *(const float4*)&ga[12];
        union { ushort4 s4[4]; uint4 v[2]; } pk;
        pk.s4[0] = cvt4(f0); pk.s4[1] = cvt4(f1); pk.s4[2] = cvt4(f2); pk.s4[3] = cvt4(f3);
        *(uint4*)&At[arow * 32 + aseg]     = pk.v[0];
        *(uint4*)&At[arow * 32 + aseg + 8] = pk.v[1];
        __syncthreads();
        bf16x8 af[4], bf[4];
        for (int mr = 0; mr < 4; mr++)
            af[mr] = *(const bf16x8*)&At[(wr * 64 + mr * 16 + l15) * 32 + q * 8];
        for (int nc = 0; nc < 4; nc++)
            bf[nc] = *(const bf16x8*)&Bt[(wc * 64 + nc * 16 + l15) * 32 + q * 8];
        for (int mr = 0; mr < 4; mr++)
            for (int nc = 0; nc < 4; nc++)
                acc[mr][nc] = __builtin_amdgcn_mfma_f32_16x16x32_bf16(af[mr], bf[nc], acc[mr][nc], 0, 0, 0);
    }
    for (int nc = 0; nc < 4; nc++) {
        int col = n0 + wc * 64 + nc * 16 + l15;
        const float* We = W1 + (size_t)NI * HID + col;
        float cv = b1[col] + We[2 * HID] + We[5 * HID] + We[8 * HID] + We[10 * HID]
                 + We[14 * HID] + 0.0625f * We[46 * HID];
        for (int mr = 0; mr < 4; mr++)
            for (int r = 0; r < 4; r++) {
                int row = m0 + wr * 64 + mr * 16 + q * 4 + r;
                C[(size_t)row * HID + col] = acc[mr][nc][r] + cv;
            }
    }
}

// ---------------------------------------------------------------------------
// Kernel 3: BARRIER-FREE fused MLP + CE. One WAVE per b (4 waves/block),
// zero __syncthreads — all LDS use is wave-private (DS ops are in-order
// within a wave).
// R7 SPILL POST-MORTEM: with constant 16-trip it-loop and no barriers the
// compiler fully unrolled/pipelined all iterations' loads -> >128 live regs
// -> scratch (WRITE_SIZE 132 MB). Fixes: unroll(disable) on the it-loop +
// plain launch_bounds(256) so the allocator sizes to the real live set.
// ---------------------------------------------------------------------------
__global__ __launch_bounds__(256) void fused_mlp(const float* __restrict__ base,
                                                 const float* __restrict__ W1,
                                                 const unsigned short* __restrict__ W2T,
                                                 const float* __restrict__ b2,
                                                 const float* __restrict__ U4f,
                                                 const int* __restrict__ BI,
                                                 float* __restrict__ loss_out) {
    __shared__ __align__(16) __bf16 S[4 * SWROWS * SR];  // 22,848 B (wave-private slabs)
    __shared__ __align__(16) float4 u4s[4][TSTEPS];      //  1,280 B
    __shared__ int dacW[4][TSTEPS];                      //    320 B

    int tid = threadIdx.x;
    int wv = tid >> 6, lane = tid & 63, l15 = lane & 15, q = lane >> 4;
    int b = blockIdx.x * 4 + wv;
    __bf16* Sw = S + wv * (SWROWS * SR);

    // --- per-b uniform scalars ---
    const int* bi = BI + b * 12;
    int selLo  = __builtin_amdgcn_readfirstlane(bi[0]);
    int selHi  = __builtin_amdgcn_readfirstlane(bi[1]);
    int cAB    = __builtin_amdgcn_readfirstlane(bi[2]);
    int cCD    = __builtin_amdgcn_readfirstlane(bi[3]);
    int cE     = __builtin_amdgcn_readfirstlane(bi[4]);
    int nAlive = __builtin_amdgcn_readfirstlane(bi[5]);
    int ns     = __builtin_amdgcn_readfirstlane(bi[6]);
    int rAn = cAB & 255,         rAo = (cAB >> 8) & 255;
    int rBn = (cAB >> 16) & 255, rBo = (cAB >> 24) & 255;
    int rCn = cCD & 255,         rCo = (cCD >> 8) & 255;
    int rDn = (cCD >> 16) & 255, rDo = (cCD >> 24) & 255;
    int rEn = cE & 255,          rEo = (cE >> 8) & 255;

    // --- wave-private LDS setup (no barrier: same-wave DS ordering) ---
    if (lane < TSTEPS) {
        u4s[wv][lane] = *(const float4*)&U4f[((size_t)b * TSTEPS + lane) * 4];
        int w = lane / 5, s5 = (lane - w * 5) * 6;
        dacW[wv][lane] = (bi[7 + w] >> s5) & 63;
    }
    if (lane < 17) *(uint4*)&Sw[20 * SR + lane * 8] = make_uint4(0, 0, 0, 0);  // zero row 20

    const float* Wx = W1 + (size_t)NI * HID;
    const __bf16* Wb = (const __bf16*)W2T;
    floatx4 acc[2][3];
    for (int a = 0; a < 2; a++) for (int c = 0; c < 3; c++) acc[a][c] = (floatx4){0.f, 0.f, 0.f, 0.f};

#pragma clang loop unroll(disable)
    for (int it = 0; it < 16; it++) {
        int j = it * 128 + 2 * lane;
        // phase A loads (all independent, issue together)
        float2 w0  = *(const float2*)&Wx[j];
        float2 w1  = *(const float2*)&Wx[HID + j];
        float2 wdl = *(const float2*)&Wx[46 * HID + j];
        float2 wch = *(const float2*)&Wx[47 * HID + j];
        float2 hb  = *(const float2*)&base[(size_t)b * HID + j];  // incl. b1 + t0 consts
        float2 d0 = {0,0}, d1 = {0,0}, d2 = {0,0}, d3 = {0,0}, d4 = {0,0};
        if (ns > 0) { float2 rn = *(const float2*)&Wx[(size_t)rAn * HID + j], ro = *(const float2*)&Wx[(size_t)rAo * HID + j]; d0.x = rn.x - ro.x; d0.y = rn.y - ro.y; }
        if (ns > 1) { float2 rn = *(const float2*)&Wx[(size_t)rBn * HID + j], ro = *(const float2*)&Wx[(size_t)rBo * HID + j]; d1.x = rn.x - ro.x; d1.y = rn.y - ro.y; }
        if (ns > 2) { float2 rn = *(const float2*)&Wx[(size_t)rCn * HID + j], ro = *(const float2*)&Wx[(size_t)rCo * HID + j]; d2.x = rn.x - ro.x; d2.y = rn.y - ro.y; }
        if (ns > 3) { float2 rn = *(const float2*)&Wx[(size_t)rDn * HID + j], ro = *(const float2*)&Wx[(size_t)rDo * HID + j]; d3.x = rn.x - ro.x; d3.y = rn.y - ro.y; }
        if (ns > 4) { float2 rn = *(const float2*)&Wx[(size_t)rEn * HID + j], ro = *(const float2*)&Wx[(size_t)rEo * HID + j]; d4.x = rn.x - ro.x; d4.y = rn.y - ro.y; }
        float hbs0 = hb.x, hbs1 = hb.y;
#pragma unroll
        for (int t = 0; t < TSTEPS; t++) {
            int sel = (t < 10) ? ((selLo >> (3 * t)) & 7) : ((selHi >> (3 * (t - 10))) & 7);
            if (sel != 7) {  // uniform scalar branch (<=5 taken)
                float2 d = (sel == 0) ? d0 : (sel == 1) ? d1 : (sel == 2) ? d2 : (sel == 3) ? d3 : d4;
                hbs0 += d.x; hbs1 += d.y;
            }
            float4 u = u4s[wv][t];   // broadcast read
            float h0 = fmaf(u.x, w0.x, fmaf(u.y, w1.x, fmaf(u.z, wdl.x, fmaf(u.w, wch.x, hbs0))));
            float h1 = fmaf(u.x, w0.y, fmaf(u.y, w1.y, fmaf(u.z, wdl.y, fmaf(u.w, wch.y, hbs1))));
            float s0 = h0 * __builtin_amdgcn_rcpf(1.f + __expf(-h0));
            float s1 = h1 * __builtin_amdgcn_rcpf(1.f + __expf(-h1));
            union { float f; unsigned u; } v0, v1;
            v0.f = s0; v1.f = s1;
            unsigned pkd = ((v0.u + 0x8000u) >> 16) | ((v1.u + 0x8000u) & 0xFFFF0000u);
            *(unsigned*)&Sw[t * SR + 2 * lane] = pkd;
        }
        // phase B: this wave's K-chunk of 128 (same-wave DS ordering, no barrier)
        int row1 = (l15 < 4) ? 16 + l15 : 20;   // row 20 is the zero row
#pragma unroll
        for (int kc = 0; kc < 4; kc++) {
            int kloc = kc * 32 + q * 8;
            bf16x8 a0 = *(const bf16x8*)&Sw[l15 * SR + kloc];
            bf16x8 a1 = *(const bf16x8*)&Sw[row1 * SR + kloc];
            int kg = it * 128 + kloc;
            bf16x8 b0  = *(const bf16x8*)&Wb[(size_t)l15 * HID + kg];
            bf16x8 b1v = *(const bf16x8*)&Wb[(size_t)(16 + l15) * HID + kg];
            bf16x8 b2v = *(const bf16x8*)&Wb[(size_t)(32 + l15) * HID + kg];
            acc[0][0] = __builtin_amdgcn_mfma_f32_16x16x32_bf16(a0, b0,  acc[0][0], 0, 0, 0);
            acc[0][1] = __builtin_amdgcn_mfma_f32_16x16x32_bf16(a0, b1v, acc[0][1], 0, 0, 0);
            acc[0][2] = __builtin_amdgcn_mfma_f32_16x16x32_bf16(a0, b2v, acc[0][2], 0, 0, 0);
            acc[1][0] = __builtin_amdgcn_mfma_f32_16x16x32_bf16(a1, b0,  acc[1][0], 0, 0, 0);
            acc[1][1] = __builtin_amdgcn_mfma_f32_16x16x32_bf16(a1, b1v, acc[1][1], 0, 0, 0);
            acc[1][2] = __builtin_amdgcn_mfma_f32_16x16x32_bf16(a1, b2v, acc[1][2], 0, 0, 0);
        }
    }

    // --- in-register CE (classes on l15 x nt; t = mt*16 + q*4 + r) ---
    float bb0 = b2[l15];
    float bb1 = b2[16 + l15];
    float bb2 = -1e30f;                      // pad classes 45..47 -> -inf
    if (l15 < 13) bb2 = b2[32 + l15];
    float ceTot = 0.f;
#pragma unroll
    for (int mt = 0; mt < 2; mt++)
#pragma unroll
        for (int r = 0; r < 4; r++) {
            int t = mt * 16 + q * 4 + r;     // per-lane
            float l0 = acc[mt][0][r] + bb0;
            float l1 = acc[mt][1][r] + bb1;
            float l2 = acc[mt][2][r] + bb2;
            int dac = dacW[wv][t < TSTEPS ? t : 0];
            float mx = fmaxf(fmaxf(l0, l1), l2);
            float tl = -1e30f;
            tl = (l15      == dac) ? l0 : tl;
            tl = (16 + l15 == dac) ? l1 : tl;
            tl = (32 + l15 == dac) ? l2 : tl;
#pragma unroll
            for (int m = 1; m <= 8; m <<= 1) {
                mx = fmaxf(mx, __shfl_xor(mx, m));
                tl = fmaxf(tl, __shfl_xor(tl, m));
            }
            float s = __expf(l0 - mx) + __expf(l1 - mx) + __expf(l2 - mx);
#pragma unroll
            for (int m = 1; m <= 8; m <<= 1) s += __shfl_xor(s, m);
            float ce = -(tl - mx - __logf(s));
            ceTot += (t < nAlive) ? ce : 0.f;
        }
    ceTot += __shfl_xor(ceTot, 16);
    ceTot += __shfl_xor(ceTot, 32);
    if (lane == 0) loss_out[b] = ceTot / (float)nAlive;
}

// ---------------------------------------------------------------------------
// Kernel 4: deterministic final reduction over 4096 per-b losses
// ---------------------------------------------------------------------------
__global__ void reduce_loss(const float* __restrict__ loss, float* __restrict__ out) {
    int tid = threadIdx.x;  // 256
    float s = 0.f;
    for (int i = tid; i < BATCH; i += 256) s += loss[i];
    for (int off = 32; off > 0; off >>= 1) s += __shfl_down(s, off, 64);
    __shared__ float wsum[4];
    if ((tid & 63) == 0) wsum[tid >> 6] = s;
    __syncthreads();
    if (tid == 0) out[0] = (wsum[0] + wsum[1] + wsum[2] + wsum[3]) * (1.0f / (float)BATCH);
}

// ---------------------------------------------------------------------------
extern "C" void kernel_launch(void* const* d_in, const int* in_sizes, int n_in,
                              void* d_out, int out_size, void* d_ws, size_t ws_size,
                              hipStream_t stream) {
    const float* fc_input = (const float*)d_in[0];
    const float* camera   = (const float*)d_in[1];
    const int*   fb       = (const int*)d_in[2];
    const int*   lr       = (const int*)d_in[3];
    const int*   jp       = (const int*)d_in[4];
    const int*   ss       = (const int*)d_in[5];
    const int*   at       = (const int*)d_in[6];
    const float* W1       = (const float*)d_in[7];
    const float* b1       = (const float*)d_in[8];
    const float* W2       = (const float*)d_in[9];
    const float* b2       = (const float*)d_in[10];
    float* out = (float*)d_out;

    char* ws = (char*)d_ws;
    unsigned short* Wt   = (unsigned short*)(ws);                       //  4,194,304 B
    float*          baseB= (float*)(ws + 4194304);                      // 33,554,432 B
    float*          U4f  = (float*)(ws + 37748736);                     //  1,310,720 B
    int*            BI   = (int*)(ws + 39059456);                       //    196,608 B
    float*          lossB= (float*)(ws + 39256064);                     //     16,384 B
    unsigned short* W2T  = (unsigned short*)(ws + 39272448);            //    196,608 B

    prep_kernel<<<2048 + 8 + 16, 256, 0, stream>>>(W1, Wt, W2, W2T,
                                                   camera, fb, lr, jp, ss, at, U4f, BI);
    gemm_base<<<dim3(HID / 128, BATCH / 128), 256, 0, stream>>>(fc_input, Wt, W1, b1, baseB);
    fused_mlp<<<BATCH / 4, 256, 0, stream>>>(baseB, W1, W2T, b2, U4f, BI, lossB);
    reduce_loss<<<1, 256, 0, stream>>>(lossB, out);
}

// Round 9
// 277.969 us; speedup vs baseline: 2.2608x; 1.1067x over previous
//
#include <hip/hip_runtime.h>

// Problem constants
#define BATCH 4096
#define NI 1024
#define HID 2048
#define TSTEPS 20
#define NA 45
#define SR 136     // fused S row stride in bf16 elems (128 + 8 pad)
#define SWROWS 21  // 20 t-rows + 1 zero row for masked A-frag reads

typedef __bf16 bf16x8 __attribute__((ext_vector_type(8)));
typedef float floatx4 __attribute__((ext_vector_type(4)));

__device__ __forceinline__ unsigned short f2bf(float x) {
    union { float f; unsigned int u; } un; un.f = x;
    unsigned int r = un.u + 0x7FFFu + ((un.u >> 16) & 1u);
    return (unsigned short)(r >> 16);
}

__device__ __forceinline__ ushort4 cvt4(float4 v) {
    ushort4 o;
    o.x = f2bf(v.x); o.y = f2bf(v.y); o.z = f2bf(v.z); o.w = f2bf(v.w);
    return o;
}

// ---------------------------------------------------------------------------
// Kernel 1 (merged prep): transpose_w1 (blocks [0,2048)), convert_w2
// (blocks [2048,2056)), scan (blocks [2056,2072)).
// scan: exact fp32 replication of the 20-step state machine. Emits per-b:
//   U4[b][20] float4 = (ac0, ac1, delta-0.0625, chosen)  [absolute state]
//   BI[b][12] ints: 0 selLo, 1 selHi (3b/t swap-slot or 7), 2 cAB, 3 cCD,
//   4 cE (packed (old<<8)|new cols), 5 nAlive (alive is monotone!), 6 ns,
//   7..10 dacPk (6b/dac, 5 per int), 11 pad.
// x-col offsets of extras: ac0=0 ac1=1 fb=2..4 lr=5..7 jp=8..9 ss=10..13
// at=14..45 delta=46 chosen=47.
// ---------------------------------------------------------------------------
__global__ void prep_kernel(const float* __restrict__ W1, unsigned short* __restrict__ Wt,
                            const float* __restrict__ W2, unsigned short* __restrict__ W2T,
                            const float* __restrict__ camera,
                            const int* __restrict__ fb_in, const int* __restrict__ lr_in,
                            const int* __restrict__ jp_in, const int* __restrict__ ss_in,
                            const int* __restrict__ at_in,
                            float* __restrict__ U4f, int* __restrict__ BI) {
    __shared__ float tile[32][33];
    int bid = blockIdx.x, tid = threadIdx.x;
    if (bid < 2048) {
        int k0 = (bid & 31) * 32, n0 = (bid >> 5) * 32;
        int tx = tid & 31, ty = tid >> 5;  // (32, 8)
        for (int i = 0; i < 4; i++)
            tile[ty + 8 * i][tx] = W1[(size_t)(k0 + ty + 8 * i) * HID + n0 + tx];
        __syncthreads();
        for (int i = 0; i < 4; i++) {
            int n = ty + 8 * i;
            Wt[(size_t)(n0 + n) * NI + k0 + tx] = f2bf(tile[tx][n]);
        }
    } else if (bid < 2056) {
        int k = (bid - 2048) * 256 + tid;  // 0..2047
        for (int n = 0; n < 48; n++)
            W2T[(size_t)n * HID + k] = (n < NA) ? f2bf(W2[(size_t)k * NA + n]) : (unsigned short)0;
    } else {
        int b = (bid - 2056) * 256 + tid;
        if (b >= BATCH) return;
        float cam0 = camera[2 * b], cam1 = camera[2 * b + 1];
        int afb = fb_in[b], alr = lr_in[b], ajp = jp_in[b], ass = ss_in[b], aat = at_in[b];
        float ac0 = 0.f, ac1 = 0.f, delta = 0.0625f;  // MIN_DELTA = 0.5/8
        int rfb = 0, rlr = 0, rjp = 0, rss = 0, rat = 0;
        bool chosen = false, commited = false;
        int cam_steps = 0;
        int chgPending = -1;
        bool camzero = (fabsf(cam0) < 1e-5f) && (fabsf(cam1) < 1e-5f);
        int ns = 0, selLo = 0, selHi = 0, nAlive = 0;
        int swapC[5] = {0, 0, 0, 0, 0};
        int dacPk[4] = {0, 0, 0, 0};
#pragma unroll
        for (int t = 0; t < TSTEPS; t++) {
            // entering step t: apply pending swap to schedule
            int sel = 7;
            if (chgPending >= 0) { swapC[ns] = chgPending; sel = ns; ns++; chgPending = -1; }
            if (t < 10) selLo |= sel << (3 * t); else selHi |= sel << (3 * (t - 10));
            ((float4*)U4f)[b * TSTEPS + t] =
                make_float4(ac0, ac1, delta - 0.0625f, chosen ? 1.f : 0.f);
            nAlive += commited ? 0 : 1;
            bool commit = (camzero || cam_steps >= 6) &&
                          rfb == afb && rlr == alr && rjp == ajp && rss == ass && rat == aat;
            int dac = 0; bool modified = commit;
            if (!modified && rfb != afb) { dac = (afb == 0 ? rfb - 1 + 6  : afb - 1 + 6 ); chgPending = ((2  + rfb) << 8) | (2  + afb); rfb = afb; modified = true; }
            if (!modified && rlr != alr) { dac = (alr == 0 ? rlr - 1 + 8  : alr - 1 + 8 ); chgPending = ((5  + rlr) << 8) | (5  + alr); rlr = alr; modified = true; }
            if (!modified && rjp != ajp) { dac = (ajp == 0 ? rjp - 1 + 10 : ajp - 1 + 10); chgPending = ((8  + rjp) << 8) | (8  + ajp); rjp = ajp; modified = true; }
            if (!modified && rss != ass) { dac = (ass == 0 ? rss - 1 + 11 : ass - 1 + 11); chgPending = ((10 + rss) << 8) | (10 + ass); rss = ass; modified = true; }
            if (!modified && rat != aat) { dac = (aat == 0 ? rat - 1 + 14 : aat - 1 + 14); chgPending = ((14 + rat) << 8) | (14 + aat); rat = aat; modified = true; }
            // NOTE: reference compares BOTH cam0 and cam1 against ac0 (as-is)
            if (!modified && !chosen &&
                (fabsf(cam0 - ac0) > delta * 2.f || fabsf(cam1 - ac0) > delta * 2.f)) {
                dac = 5; delta = fminf(delta * 2.f, 0.5f); modified = true;
            }
            if (!modified) {
                bool incX = cam0 >= ac0, incY = cam1 >= ac1;
                dac = 1 + (incX ? 1 : 0) + (incY ? 2 : 0);
                ac0 += incX ? delta : -delta;
                ac1 += incY ? delta : -delta;
                delta *= 0.5f;
                chosen = true;
                cam_steps++;
            }
            commited = commited || commit;
            dacPk[t / 5] |= dac << (6 * (t % 5));
        }
        int* o = BI + b * 12;
        o[0] = selLo; o[1] = selHi;
        o[2] = swapC[0] | (swapC[1] << 16);
        o[3] = swapC[2] | (swapC[3] << 16);
        o[4] = swapC[4];
        o[5] = nAlive; o[6] = ns;
        o[7] = dacPk[0]; o[8] = dacPk[1]; o[9] = dacPk[2]; o[10] = dacPk[3];
        o[11] = 0;
    }
}

// ---------------------------------------------------------------------------
// Kernel 2: base[4096][2048] = fc_input(fp32, converted in-register) @
// W1[:1024] (bf16 MFMA). Epilogue folds t=0 constants: + b1 + initial
// one-hot rows (2,5,8,10,14) + 0.0625*w_delta.
// ---------------------------------------------------------------------------
__global__ __launch_bounds__(256) void gemm_base(const float* __restrict__ A,
                                                 const unsigned short* __restrict__ Wt,
                                                 const float* __restrict__ W1,
                                                 const float* __restrict__ b1,
                                                 float* __restrict__ C) {
    __shared__ __align__(16) __bf16 At[128 * 32];
    __shared__ __align__(16) __bf16 Bt[128 * 32];
    int bn = blockIdx.x, bm = blockIdx.y;
    int m0 = bm * 128, n0 = bn * 128;
    int tid = threadIdx.x;
    int wave = tid >> 6, lane = tid & 63;
    int wr = wave >> 1, wc = wave & 1;
    int l15 = lane & 15, q = lane >> 4;
    floatx4 acc[4][4];
    for (int a = 0; a < 4; a++) for (int c = 0; c < 4; c++) acc[a][c] = (floatx4){0.f, 0.f, 0.f, 0.f};
    int arow = tid >> 1, aseg = (tid & 1) * 16;
    for (int k0 = 0; k0 < NI; k0 += 32) {
        __syncthreads();
#pragma unroll
        for (int i = 0; i < 2; i++) {
            int c = i * 256 + tid;
            int row = c >> 2, quarter = c & 3;
            const unsigned short* gB = &Wt[(size_t)(n0 + row) * NI + k0 + quarter * 8];
            __builtin_amdgcn_global_load_lds(
                (const __attribute__((address_space(1))) unsigned int*)gB,
                (__attribute__((address_space(3))) unsigned int*)&Bt[c * 8], 16, 0, 0);
        }
        const float* ga = &A[(size_t)(m0 + arow) * NI + k0 + aseg];
        float4 f0 = *(const float4*)&ga[0];
        float4 f1 = *(const float4*)&ga[4];
        float4 f2 = *(const float4*)&ga[8];
        float4 f3 = *(const float4*)&ga[12];
        union { ushort4 s4[4]; uint4 v[2]; } pk;
        pk.s4[0] = cvt4(f0); pk.s4[1] = cvt4(f1); pk.s4[2] = cvt4(f2); pk.s4[3] = cvt4(f3);
        *(uint4*)&At[arow * 32 + aseg]     = pk.v[0];
        *(uint4*)&At[arow * 32 + aseg + 8] = pk.v[1];
        __syncthreads();
        bf16x8 af[4], bf[4];
        for (int mr = 0; mr < 4; mr++)
            af[mr] = *(const bf16x8*)&At[(wr * 64 + mr * 16 + l15) * 32 + q * 8];
        for (int nc = 0; nc < 4; nc++)
            bf[nc] = *(const bf16x8*)&Bt[(wc * 64 + nc * 16 + l15) * 32 + q * 8];
        for (int mr = 0; mr < 4; mr++)
            for (int nc = 0; nc < 4; nc++)
                acc[mr][nc] = __builtin_amdgcn_mfma_f32_16x16x32_bf16(af[mr], bf[nc], acc[mr][nc], 0, 0, 0);
    }
    for (int nc = 0; nc < 4; nc++) {
        int col = n0 + wc * 64 + nc * 16 + l15;
        const float* We = W1 + (size_t)NI * HID + col;
        float cv = b1[col] + We[2 * HID] + We[5 * HID] + We[8 * HID] + We[10 * HID]
                 + We[14 * HID] + 0.0625f * We[46 * HID];
        for (int mr = 0; mr < 4; mr++)
            for (int r = 0; r < 4; r++) {
                int row = m0 + wr * 64 + mr * 16 + q * 4 + r;
                C[(size_t)row * HID + col] = acc[mr][nc][r] + cv;
            }
    }
}

// ---------------------------------------------------------------------------
// Kernel 3: BARRIER-FREE fused MLP + CE. One WAVE per b (4 waves/block),
// zero __syncthreads — all LDS use is wave-private.
// R8 POST-MORTEM: VGPR 128 arch + ~32 acc = ~160 unified -> past the 128
// halving boundary -> only 2 waves/SIMD (Occupancy 20%). Fixes this round:
// (a) launch_bounds(256,4): total<=128 -> 4 waves/SIMD (it-loop unroll stays
// disabled so the live set ~85 fits without R7's spill);
// (b) alive is monotone: t-loop breaks at nAlive (mean ~11 of 20) — S slab
// zeroed once at entry, dead logit rows masked in CE;
// (c) skip the second M-tile MFMAs when nAlive <= 16 (wave-uniform).
// ---------------------------------------------------------------------------
__global__ __launch_bounds__(256, 4) void fused_mlp(const float* __restrict__ base,
                                                    const float* __restrict__ W1,
                                                    const unsigned short* __restrict__ W2T,
                                                    const float* __restrict__ b2,
                                                    const float* __restrict__ U4f,
                                                    const int* __restrict__ BI,
                                                    float* __restrict__ loss_out) {
    __shared__ __align__(16) __bf16 S[4 * SWROWS * SR];  // 22,848 B (wave-private slabs)
    __shared__ __align__(16) float4 u4s[4][TSTEPS];      //  1,280 B
    __shared__ int dacW[4][TSTEPS];                      //    320 B

    int tid = threadIdx.x;
    int wv = tid >> 6, lane = tid & 63, l15 = lane & 15, q = lane >> 4;
    int b = blockIdx.x * 4 + wv;
    __bf16* Sw = S + wv * (SWROWS * SR);

    // --- per-b uniform scalars ---
    const int* bi = BI + b * 12;
    int selLo  = __builtin_amdgcn_readfirstlane(bi[0]);
    int selHi  = __builtin_amdgcn_readfirstlane(bi[1]);
    int cAB    = __builtin_amdgcn_readfirstlane(bi[2]);
    int cCD    = __builtin_amdgcn_readfirstlane(bi[3]);
    int cE     = __builtin_amdgcn_readfirstlane(bi[4]);
    int nAlive = __builtin_amdgcn_readfirstlane(bi[5]);
    int ns     = __builtin_amdgcn_readfirstlane(bi[6]);
    int rAn = cAB & 255,         rAo = (cAB >> 8) & 255;
    int rBn = (cAB >> 16) & 255, rBo = (cAB >> 24) & 255;
    int rCn = cCD & 255,         rCo = (cCD >> 8) & 255;
    int rDn = (cCD >> 16) & 255, rDo = (cCD >> 24) & 255;
    int rEn = cE & 255,          rEo = (cE >> 8) & 255;
    bool doHi = nAlive > 16;

    // --- wave-private LDS setup (no barrier: same-wave DS ordering) ---
    {   // zero entire slab: rows >= nAlive (incl. zero row 20) must read 0
        uint4* z = (uint4*)Sw;   // 21*SR*2 = 5712 B = 357 uint4
        for (int k = lane; k < 357; k += 64) z[k] = make_uint4(0, 0, 0, 0);
    }
    if (lane < TSTEPS) {
        u4s[wv][lane] = *(const float4*)&U4f[((size_t)b * TSTEPS + lane) * 4];
        int w = lane / 5, s5 = (lane - w * 5) * 6;
        dacW[wv][lane] = (bi[7 + w] >> s5) & 63;
    }

    const float* Wx = W1 + (size_t)NI * HID;
    const __bf16* Wb = (const __bf16*)W2T;
    floatx4 acc[2][3];
    for (int a = 0; a < 2; a++) for (int c = 0; c < 3; c++) acc[a][c] = (floatx4){0.f, 0.f, 0.f, 0.f};

#pragma clang loop unroll(disable)
    for (int it = 0; it < 16; it++) {
        int j = it * 128 + 2 * lane;
        // phase A loads (all independent, issue together)
        float2 w0  = *(const float2*)&Wx[j];
        float2 w1  = *(const float2*)&Wx[HID + j];
        float2 wdl = *(const float2*)&Wx[46 * HID + j];
        float2 wch = *(const float2*)&Wx[47 * HID + j];
        float2 hb  = *(const float2*)&base[(size_t)b * HID + j];  // incl. b1 + t0 consts
        float2 d0 = {0,0}, d1 = {0,0}, d2 = {0,0}, d3 = {0,0}, d4 = {0,0};
        if (ns > 0) { float2 rn = *(const float2*)&Wx[(size_t)rAn * HID + j], ro = *(const float2*)&Wx[(size_t)rAo * HID + j]; d0.x = rn.x - ro.x; d0.y = rn.y - ro.y; }
        if (ns > 1) { float2 rn = *(const float2*)&Wx[(size_t)rBn * HID + j], ro = *(const float2*)&Wx[(size_t)rBo * HID + j]; d1.x = rn.x - ro.x; d1.y = rn.y - ro.y; }
        if (ns > 2) { float2 rn = *(const float2*)&Wx[(size_t)rCn * HID + j], ro = *(const float2*)&Wx[(size_t)rCo * HID + j]; d2.x = rn.x - ro.x; d2.y = rn.y - ro.y; }
        if (ns > 3) { float2 rn = *(const float2*)&Wx[(size_t)rDn * HID + j], ro = *(const float2*)&Wx[(size_t)rDo * HID + j]; d3.x = rn.x - ro.x; d3.y = rn.y - ro.y; }
        if (ns > 4) { float2 rn = *(const float2*)&Wx[(size_t)rEn * HID + j], ro = *(const float2*)&Wx[(size_t)rEo * HID + j]; d4.x = rn.x - ro.x; d4.y = rn.y - ro.y; }
        float hbs0 = hb.x, hbs1 = hb.y;
#pragma unroll
        for (int t = 0; t < TSTEPS; t++) {
            if (t >= nAlive) break;          // uniform scalar early-exit
            int sel = (t < 10) ? ((selLo >> (3 * t)) & 7) : ((selHi >> (3 * (t - 10))) & 7);
            if (sel != 7) {  // uniform scalar branch (<=5 taken)
                float2 d = (sel == 0) ? d0 : (sel == 1) ? d1 : (sel == 2) ? d2 : (sel == 3) ? d3 : d4;
                hbs0 += d.x; hbs1 += d.y;
            }
            float4 u = u4s[wv][t];   // broadcast read
            float h0 = fmaf(u.x, w0.x, fmaf(u.y, w1.x, fmaf(u.z, wdl.x, fmaf(u.w, wch.x, hbs0))));
            float h1 = fmaf(u.x, w0.y, fmaf(u.y, w1.y, fmaf(u.z, wdl.y, fmaf(u.w, wch.y, hbs1))));
            float s0 = h0 * __builtin_amdgcn_rcpf(1.f + __expf(-h0));
            float s1 = h1 * __builtin_amdgcn_rcpf(1.f + __expf(-h1));
            union { float f; unsigned u; } v0, v1;
            v0.f = s0; v1.f = s1;
            unsigned pkd = ((v0.u + 0x8000u) >> 16) | ((v1.u + 0x8000u) & 0xFFFF0000u);
            *(unsigned*)&Sw[t * SR + 2 * lane] = pkd;
        }
        // phase B: this wave's K-chunk of 128 (same-wave DS ordering, no barrier)
        int row1 = (l15 < 4) ? 16 + l15 : 20;   // row 20 is the zero row
#pragma unroll
        for (int kc = 0; kc < 4; kc++) {
            int kloc = kc * 32 + q * 8;
            bf16x8 a0 = *(const bf16x8*)&Sw[l15 * SR + kloc];
            int kg = it * 128 + kloc;
            bf16x8 b0  = *(const bf16x8*)&Wb[(size_t)l15 * HID + kg];
            bf16x8 b1v = *(const bf16x8*)&Wb[(size_t)(16 + l15) * HID + kg];
            bf16x8 b2v = *(const bf16x8*)&Wb[(size_t)(32 + l15) * HID + kg];
            acc[0][0] = __builtin_amdgcn_mfma_f32_16x16x32_bf16(a0, b0,  acc[0][0], 0, 0, 0);
            acc[0][1] = __builtin_amdgcn_mfma_f32_16x16x32_bf16(a0, b1v, acc[0][1], 0, 0, 0);
            acc[0][2] = __builtin_amdgcn_mfma_f32_16x16x32_bf16(a0, b2v, acc[0][2], 0, 0, 0);
            if (doHi) {                       // rows 16..19 only if alive past 16
                bf16x8 a1 = *(const bf16x8*)&Sw[row1 * SR + kloc];
                acc[1][0] = __builtin_amdgcn_mfma_f32_16x16x32_bf16(a1, b0,  acc[1][0], 0, 0, 0);
                acc[1][1] = __builtin_amdgcn_mfma_f32_16x16x32_bf16(a1, b1v, acc[1][1], 0, 0, 0);
                acc[1][2] = __builtin_amdgcn_mfma_f32_16x16x32_bf16(a1, b2v, acc[1][2], 0, 0, 0);
            }
        }
    }

    // --- in-register CE (classes on l15 x nt; t = mt*16 + q*4 + r) ---
    float bb0 = b2[l15];
    float bb1 = b2[16 + l15];
    float bb2 = -1e30f;                      // pad classes 45..47 -> -inf
    if (l15 < 13) bb2 = b2[32 + l15];
    float ceTot = 0.f;
#pragma unroll
    for (int mt = 0; mt < 2; mt++)
#pragma unroll
        for (int r = 0; r < 4; r++) {
            int t = mt * 16 + q * 4 + r;     // per-lane
            float l0 = acc[mt][0][r] + bb0;
            float l1 = acc[mt][1][r] + bb1;
            float l2 = acc[mt][2][r] + bb2;
            int dac = dacW[wv][t < TSTEPS ? t : 0];
            float mx = fmaxf(fmaxf(l0, l1), l2);
            float tl = -1e30f;
            tl = (l15      == dac) ? l0 : tl;
            tl = (16 + l15 == dac) ? l1 : tl;
            tl = (32 + l15 == dac) ? l2 : tl;
#pragma unroll
            for (int m = 1; m <= 8; m <<= 1) {
                mx = fmaxf(mx, __shfl_xor(mx, m));
                tl = fmaxf(tl, __shfl_xor(tl, m));
            }
            float s = __expf(l0 - mx) + __expf(l1 - mx) + __expf(l2 - mx);
#pragma unroll
            for (int m = 1; m <= 8; m <<= 1) s += __shfl_xor(s, m);
            float ce = -(tl - mx - __logf(s));
            ceTot += (t < nAlive) ? ce : 0.f;
        }
    ceTot += __shfl_xor(ceTot, 16);
    ceTot += __shfl_xor(ceTot, 32);
    if (lane == 0) loss_out[b] = ceTot / (float)nAlive;
}

// ---------------------------------------------------------------------------
// Kernel 4: deterministic final reduction over 4096 per-b losses
// ---------------------------------------------------------------------------
__global__ void reduce_loss(const float* __restrict__ loss, float* __restrict__ out) {
    int tid = threadIdx.x;  // 256
    float s = 0.f;
    for (int i = tid; i < BATCH; i += 256) s += loss[i];
    for (int off = 32; off > 0; off >>= 1) s += __shfl_down(s, off, 64);
    __shared__ float wsum[4];
    if ((tid & 63) == 0) wsum[tid >> 6] = s;
    __syncthreads();
    if (tid == 0) out[0] = (wsum[0] + wsum[1] + wsum[2] + wsum[3]) * (1.0f / (float)BATCH);
}

// ---------------------------------------------------------------------------
extern "C" void kernel_launch(void* const* d_in, const int* in_sizes, int n_in,
                              void* d_out, int out_size, void* d_ws, size_t ws_size,
                              hipStream_t stream) {
    const float* fc_input = (const float*)d_in[0];
    const float* camera   = (const float*)d_in[1];
    const int*   fb       = (const int*)d_in[2];
    const int*   lr       = (const int*)d_in[3];
    const int*   jp       = (const int*)d_in[4];
    const int*   ss       = (const int*)d_in[5];
    const int*   at       = (const int*)d_in[6];
    const float* W1       = (const float*)d_in[7];
    const float* b1       = (const float*)d_in[8];
    const float* W2       = (const float*)d_in[9];
    const float* b2       = (const float*)d_in[10];
    float* out = (float*)d_out;

    char* ws = (char*)d_ws;
    unsigned short* Wt   = (unsigned short*)(ws);                       //  4,194,304 B
    float*          baseB= (float*)(ws + 4194304);                      // 33,554,432 B
    float*          U4f  = (float*)(ws + 37748736);                     //  1,310,720 B
    int*            BI   = (int*)(ws + 39059456);                       //    196,608 B
    float*          lossB= (float*)(ws + 39256064);                     //     16,384 B
    unsigned short* W2T  = (unsigned short*)(ws + 39272448);            //    196,608 B

    prep_kernel<<<2048 + 8 + 16, 256, 0, stream>>>(W1, Wt, W2, W2T,
                                                   camera, fb, lr, jp, ss, at, U4f, BI);
    gemm_base<<<dim3(HID / 128, BATCH / 128), 256, 0, stream>>>(fc_input, Wt, W1, b1, baseB);
    fused_mlp<<<BATCH / 4, 256, 0, stream>>>(baseB, W1, W2T, b2, U4f, BI, lossB);
    reduce_loss<<<1, 256, 0, stream>>>(lossB, out);
}